// Round 1
// baseline (241.357 us; speedup 1.0000x reference)
//
#include <hip/hip_runtime.h>

// QWTForward: the reference's "filtering" is exactly x * sum(h) (its own
// comment says so), and downsample is linear, so every one of the 16 output
// blocks is (S_A * S_B) * D where D = bicubic-downsample(image) and the S's
// are the four filter sums. One fused memory-bound kernel:
//   read 50 MB image, compute D once per pixel, write 16 scaled copies (201 MB).

#define BW0 -0.09375f
#define BW1  0.59375f
#define BW2  0.59375f
#define BW3 -0.09375f

#define H_IN  512
#define W_IN  512
#define H_OUT 256
#define W_OUT 256
#define PLANE_OUT (H_OUT * W_OUT)          // 65536
#define TENSOR_STRIDE (16 * 12 * PLANE_OUT) // 12582912 floats per out tensor

__global__ __launch_bounds__(256) void qwt_fused_kernel(
    const float* __restrict__ img,
    const float* __restrict__ gl, const float* __restrict__ gh,
    const float* __restrict__ fl, const float* __restrict__ fh,
    float* __restrict__ out)
{
    __shared__ float s_scale[16];

    const int tid = threadIdx.x;

    // ---- wave 0: filter sums + 16 scale products -> LDS ----
    if (tid < 64) {
        float vgl = 0.f, vgh = 0.f, vfl = 0.f, vfh = 0.f;
        if (tid < 30) { vgl = gl[tid]; vgh = gh[tid]; vfl = fl[tid]; vfh = fh[tid]; }
        #pragma unroll
        for (int m = 32; m >= 1; m >>= 1) {
            vgl += __shfl_xor(vgl, m);
            vgh += __shfl_xor(vgh, m);
            vfl += __shfl_xor(vfl, m);
            vfh += __shfl_xor(vfh, m);
        }
        if (tid < 16) {
            const int t = tid >> 2, cb = tid & 3;
            // A: which downsampled tensor (gl_d/fl_d for out0/1, gh_d/fh_d for out2/3)
            const float A = (t < 2) ? ((cb & 1) ? vfl : vgl)
                                    : ((cb & 1) ? vfh : vgh);
            // B: second-level filter (g* for cb<2, f* for cb>=2; l for even t, h for odd t)
            const float B = (t & 1) ? ((cb < 2) ? vgh : vfh)
                                    : ((cb < 2) ? vgl : vfl);
            s_scale[tid] = A * B;
        }
    }
    __syncthreads();

    // ---- each thread: one float4 of D = downsample(image) ----
    // idx -> (b, c, h, w4): 64 w-groups x 256 h x 48 planes = 786432 threads
    const int idx = blockIdx.x * 256 + tid;
    const int w4 = idx & 63;
    const int h  = (idx >> 6) & 255;
    const int bc = idx >> 14;            // b*3 + c, 0..47
    const int c  = bc % 3;
    const int b  = bc / 3;

    const float* plane = img + (size_t)bc * (H_IN * W_IN);

    // 4 clamped source rows: 2h-1 .. 2h+2
    int r[4];
    #pragma unroll
    for (int i = 0; i < 4; ++i) {
        int rr = 2 * h - 1 + i;
        r[i] = rr < 0 ? 0 : (rr > H_IN - 1 ? H_IN - 1 : rr);
    }

    const int cbase = w4 * 8;            // cols 8w..8w+7 always in-bounds
    int clo = cbase - 1; if (clo < 0) clo = 0;
    int chi = cbase + 8; if (chi > W_IN - 1) chi = W_IN - 1;

    float hv[4][4];
    #pragma unroll
    for (int i = 0; i < 4; ++i) {
        const float* rowp = plane + (size_t)r[i] * W_IN;
        const float4 a  = *(const float4*)(rowp + cbase);
        const float4 b4 = *(const float4*)(rowp + cbase + 4);
        const float v0 = rowp[clo];
        const float v9 = rowp[chi];
        const float v1 = a.x,  v2 = a.y,  v3 = a.z,  v4 = a.w;
        const float v5 = b4.x, v6 = b4.y, v7 = b4.z, v8 = b4.w;
        hv[i][0] = BW0 * v0 + BW1 * v1 + BW2 * v2 + BW3 * v3;
        hv[i][1] = BW0 * v2 + BW1 * v3 + BW2 * v4 + BW3 * v5;
        hv[i][2] = BW0 * v4 + BW1 * v5 + BW2 * v6 + BW3 * v7;
        hv[i][3] = BW0 * v6 + BW1 * v7 + BW2 * v8 + BW3 * v9;
    }

    float d[4];
    #pragma unroll
    for (int j = 0; j < 4; ++j)
        d[j] = BW0 * hv[0][j] + BW1 * hv[1][j] + BW2 * hv[2][j] + BW3 * hv[3][j];

    // ---- 16 coalesced float4 stores: out[t][b][cb*3+c][h][w4*4..+3] ----
    const size_t obase = (size_t)b * (12 * PLANE_OUT)
                       + (size_t)c * PLANE_OUT
                       + (size_t)h * W_OUT
                       + (size_t)(w4 * 4);
    #pragma unroll
    for (int t = 0; t < 4; ++t) {
        #pragma unroll
        for (int cb = 0; cb < 4; ++cb) {
            const float s = s_scale[t * 4 + cb];
            float4 o;
            o.x = d[0] * s; o.y = d[1] * s; o.z = d[2] * s; o.w = d[3] * s;
            *(float4*)(out + (size_t)t * TENSOR_STRIDE
                           + obase
                           + (size_t)cb * (3 * PLANE_OUT)) = o;
        }
    }
}

extern "C" void kernel_launch(void* const* d_in, const int* in_sizes, int n_in,
                              void* d_out, int out_size, void* d_ws, size_t ws_size,
                              hipStream_t stream) {
    const float* img = (const float*)d_in[0];
    const float* gl  = (const float*)d_in[1];
    const float* gh  = (const float*)d_in[2];
    const float* fl  = (const float*)d_in[3];
    const float* fh  = (const float*)d_in[4];
    float* out = (float*)d_out;

    // 16*3*256*256 output pixels of D, 4 per thread -> 786432 threads
    const int threads = 256;
    const int blocks  = (16 * 3 * 256 * 256 / 4) / threads; // 3072
    qwt_fused_kernel<<<blocks, threads, 0, stream>>>(img, gl, gh, fl, fh, out);
}